// Round 2
// 618.584 us; speedup vs baseline: 1.0376x; 1.0376x over previous
//
#include <hip/hip_runtime.h>
#include <hip/hip_bf16.h>

#define IN_F 4096
#define OUT_F 4096
#define M_TOK 8192
#define RANK 16

#define CONV_BLOCKS (M_TOK * IN_F / (8 * 256))   // 16384
#define DEQ_BLOCKS  2048

typedef __attribute__((ext_vector_type(4))) float f32x4;
typedef __attribute__((ext_vector_type(8))) short short8;

struct alignas(16) bf16x8_s { __hip_bfloat16 v[8]; };

// ---------------------------------------------------------------------------
// Kernel 1 (merged prep) — UNCHANGED this round (next target: ~280us vs
// ~60us BW floor; left alone for clean attribution of the GEMM rewrite):
//  blocks [0, CONV_BLOCKS): streaming convert x fp32 -> bf16
//  blocks [CONV_BLOCKS, +DEQ_BLOCKS): dequant int4 codes -> bf16 with the
//    rank-16 LoRA folded in:
//    W[o][i] = bf16( scales[o][i/64]*(q-8) + 2*sum_r A[i][r]*B[r][o] )
// ---------------------------------------------------------------------------
__global__ __launch_bounds__(256) void prep_kernel(
    const float* __restrict__ x,
    const int* __restrict__ q,
    const float* __restrict__ scales,
    const float* __restrict__ lA,   // [IN_F][RANK]
    const float* __restrict__ lB,   // [RANK][OUT_F]
    __hip_bfloat16* __restrict__ xb,
    __hip_bfloat16* __restrict__ W) {
    const int tid = threadIdx.x;

    if (blockIdx.x < CONV_BLOCKS) {
        size_t base = ((size_t)blockIdx.x * 256 + tid) * 8;
        float4 v0 = *(const float4*)(x + base);
        float4 v1 = *(const float4*)(x + base + 4);
        bf16x8_s r;
        r.v[0] = __float2bfloat16(v0.x);
        r.v[1] = __float2bfloat16(v0.y);
        r.v[2] = __float2bfloat16(v0.z);
        r.v[3] = __float2bfloat16(v0.w);
        r.v[4] = __float2bfloat16(v1.x);
        r.v[5] = __float2bfloat16(v1.y);
        r.v[6] = __float2bfloat16(v1.z);
        r.v[7] = __float2bfloat16(v1.w);
        *(bf16x8_s*)(xb + base) = r;
        return;
    }

    const int bid = blockIdx.x - CONV_BLOCKS;    // 0..2047
    const int o0 = (bid >> 1) * 4;               // block-uniform
    const int i0 = (bid & 1) * 2048 + tid * 8;

    float bw[16][4];
#pragma unroll
    for (int r = 0; r < 16; ++r)
#pragma unroll
        for (int oi = 0; oi < 4; ++oi)
            bw[r][oi] = 2.0f * lB[(size_t)r * OUT_F + o0 + oi];

    float fold[4][8];
#pragma unroll
    for (int e = 0; e < 8; ++e) {
        const float* ar = lA + (size_t)(i0 + e) * RANK;
        float4 a0 = *(const float4*)(ar + 0);
        float4 a1 = *(const float4*)(ar + 4);
        float4 a2 = *(const float4*)(ar + 8);
        float4 a3 = *(const float4*)(ar + 12);
#pragma unroll
        for (int oi = 0; oi < 4; ++oi) {
            float f = a0.x * bw[0][oi] + a0.y * bw[1][oi]
                    + a0.z * bw[2][oi] + a0.w * bw[3][oi]
                    + a1.x * bw[4][oi] + a1.y * bw[5][oi]
                    + a1.z * bw[6][oi] + a1.w * bw[7][oi]
                    + a2.x * bw[8][oi] + a2.y * bw[9][oi]
                    + a2.z * bw[10][oi] + a2.w * bw[11][oi]
                    + a3.x * bw[12][oi] + a3.y * bw[13][oi]
                    + a3.z * bw[14][oi] + a3.w * bw[15][oi];
            fold[oi][e] = f;
        }
    }

#pragma unroll
    for (int oi = 0; oi < 4; ++oi) {
        const int o = o0 + oi;
        const float s = scales[o * 64 + (i0 >> 6)];
        const int4* qp = (const int4*)(q + (size_t)o * IN_F + i0);
        int4 q0 = qp[0];
        int4 q1 = qp[1];
        bf16x8_s r;
        r.v[0] = __float2bfloat16(s * (float)(q0.x - 8) + fold[oi][0]);
        r.v[1] = __float2bfloat16(s * (float)(q0.y - 8) + fold[oi][1]);
        r.v[2] = __float2bfloat16(s * (float)(q0.z - 8) + fold[oi][2]);
        r.v[3] = __float2bfloat16(s * (float)(q0.w - 8) + fold[oi][3]);
        r.v[4] = __float2bfloat16(s * (float)(q1.x - 8) + fold[oi][4]);
        r.v[5] = __float2bfloat16(s * (float)(q1.y - 8) + fold[oi][5]);
        r.v[6] = __float2bfloat16(s * (float)(q1.z - 8) + fold[oi][6]);
        r.v[7] = __float2bfloat16(s * (float)(q1.w - 8) + fold[oi][7]);
        *(bf16x8_s*)(W + (size_t)o * IN_F + i0) = r;
    }
}

// ---------------------------------------------------------------------------
// Kernel 2: 256x256 8-phase GEMM (guide §5 template: T1 XCD-swizzle +
// T2 LDS XOR-swizzle + T3/T4 8-phase counted-vmcnt + T5 setprio).
//   out[m][n] = sum_k xb[m][k]*Wq[n][k] + bias[n]
// Geometry: BM=BN=256, BK=64, 512 thr = 8 waves (2M x 4N), per-wave C =
// 128x64 as 8x4 frags of 16x16 (mfma_f32_16x16x32_bf16). LDS = 128 KiB
// (2 dbuf x [A 256x64 | B 256x64] bf16), staged as 4 half-tiles/K-tile,
// 2 global_load_lds (16B) per half-tile per wave.
//
// Phase schedule per K-tile t (quadrant order (mh,nh)=(0,0),(0,1),(1,0),(1,1)):
//   p0: read A(mh0)+B(nh0); stage A1(t+1)   [A1 region of buf[(t+1)&1] free]
//   p1: read B(nh1), keep A; stage B1(t+1)
//   p2: read A(mh1)+B(nh0); stage A0(t+2)   [A0(t) last read in p1]
//   p3: read B(nh1), keep A; stage B0(t+2); s_waitcnt vmcnt(4)
// vmcnt(4) = 2 loads/half x 2 halves still in flight (p2,p3 of this tile);
// everything older (incl. all of tile t+1) has landed. Never vmcnt(0) in loop.
// Race-safety: every staged region's last reader drained at that phase's
// lgkmcnt(0), which precedes the end-barrier admitting the staging phase.
// ---------------------------------------------------------------------------
#define BK 64
#define NT (IN_F / BK)   // 64 K-tiles

__device__ __forceinline__ short8 ldfrag(const short* p, int half, int row, int gran) {
    // swizzled read: LDS granule slot (gran ^ (row&7)) holds global granule gran
    return *(const short8*)(p + half * 8192 + row * 64 + ((gran ^ (row & 7)) * 8));
}

// one half-tile stage: 128 rows x 64 cols bf16, 2 issues x (8 waves x 8 rows).
// LDS dest is linear (wave-uniform base + lane*16B); the st-swizzle is applied
// by permuting the GLOBAL source granule (rule 21: both-sides-or-neither).
#define STAGE(LDSbuf, SRC, ROW0, K0)                                          \
    {                                                                         \
        _Pragma("unroll")                                                     \
        for (int j = 0; j < 2; ++j) {                                         \
            const __hip_bfloat16* g = (SRC) +                                 \
                (size_t)((ROW0) + j * 64 + wave * 8 + srow) * IN_F + (K0) + sgc; \
            __builtin_amdgcn_global_load_lds(                                 \
                (const __attribute__((address_space(1))) void*)g,             \
                (__attribute__((address_space(3))) void*)((LDSbuf) + (j * 64 + wave * 8) * 64), \
                16, 0, 0);                                                    \
        }                                                                     \
    }

#define PHASE(ABUF, BBUF, MH, NH, READA, STAGE_CODE, WAITCODE)                \
    {                                                                         \
        if (READA) {                                                          \
            _Pragma("unroll") for (int f = 0; f < 4; ++f)                     \
            _Pragma("unroll") for (int kk = 0; kk < 2; ++kk)                  \
                fa[f][kk] = ldfrag(ABUF, MH, wm * 64 + f * 16 + fr, kk * 4 + fc); \
        }                                                                     \
        _Pragma("unroll") for (int f = 0; f < 2; ++f)                         \
        _Pragma("unroll") for (int kk = 0; kk < 2; ++kk)                      \
            fb[f][kk] = ldfrag(BBUF, NH, wn * 32 + f * 16 + fr, kk * 4 + fc); \
        STAGE_CODE;                                                           \
        WAITCODE;                                                             \
        __builtin_amdgcn_s_barrier();                                         \
        asm volatile("s_waitcnt lgkmcnt(0)" ::: "memory");                    \
        __builtin_amdgcn_sched_barrier(0);                                    \
        __builtin_amdgcn_s_setprio(1);                                        \
        _Pragma("unroll") for (int f = 0; f < 4; ++f)                         \
        _Pragma("unroll") for (int g2 = 0; g2 < 2; ++g2)                      \
        _Pragma("unroll") for (int kk = 0; kk < 2; ++kk)                      \
            acc[(MH) * 4 + f][(NH) * 2 + g2] =                                \
                __builtin_amdgcn_mfma_f32_16x16x32_bf16(                      \
                    fa[f][kk], fb[g2][kk], acc[(MH) * 4 + f][(NH) * 2 + g2], 0, 0, 0); \
        __builtin_amdgcn_s_setprio(0);                                        \
        __builtin_amdgcn_s_barrier();                                         \
    }

__global__ __launch_bounds__(512, 2) void qlora_gemm_kernel(
    const __hip_bfloat16* __restrict__ xb,   // [M_TOK][IN_F]
    const __hip_bfloat16* __restrict__ Wq,   // [OUT_F][IN_F]  (B^T layout)
    const float* __restrict__ bias,          // [OUT_F]
    float* __restrict__ out) {               // [M_TOK][OUT_F]
    __shared__ __hip_bfloat16 As[2][16384];  // [dbuf][half(2) x 128 x 64] = 64 KB
    __shared__ __hip_bfloat16 Bs[2][16384];  // 64 KB

    const int tid  = threadIdx.x;
    const int wave = tid >> 6;
    const int lane = tid & 63;
    const int wm = wave >> 2;                // 0..1
    const int wn = wave & 3;                 // 0..3

    // T1: bijective XCD swizzle (nwg=512, 512%8==0): XCD x gets 64 contiguous wgids
    const int wg = ((int)blockIdx.x & 7) * 64 + ((int)blockIdx.x >> 3);
    const int bx = wg & 15;                  // 16 N-tiles
    const int by = wg >> 4;                  // 32 M-tiles
    const int m0 = by * 256;
    const int n0 = bx * 256;

    f32x4 acc[8][4];
#pragma unroll
    for (int i = 0; i < 8; ++i)
#pragma unroll
        for (int j = 0; j < 4; ++j)
            acc[i][j] = (f32x4){0.f, 0.f, 0.f, 0.f};

    // staging lane geometry: row-in-chunk = lane>>3; source granule permuted
    // so LDS slot p of row r holds global granule (p ^ (r&7))
    const int srow = lane >> 3;
    const int sgc  = ((lane & 7) ^ srow) * 8;

    // fragment read geometry (16x16x32): row = lane&15, k-granule = lane>>4.
    // 16 rows x XOR(row&7) -> 2 rows/granule-slot = 2-way = free (m136).
    const int fr = lane & 15;
    const int fc = lane >> 4;

    const short* A0p = (const short*)As[0];
    const short* A1p = (const short*)As[1];
    const short* B0p = (const short*)Bs[0];
    const short* B1p = (const short*)Bs[1];

    short8 fa[4][2];
    short8 fb[2][2];

    // prologue: tile0 all 4 halves -> buf0; tile1 A0,B0 -> buf1 (A1,B1 of
    // tile1 staged in tile0's p0/p1, matching steady state)
    STAGE(As[0],        xb, m0,       0);
    STAGE(Bs[0],        Wq, n0,       0);
    STAGE(As[0] + 8192, xb, m0 + 128, 0);
    STAGE(Bs[0] + 8192, Wq, n0 + 128, 0);
    STAGE(As[1],        xb, m0,       BK);
    STAGE(Bs[1],        Wq, n0,       BK);
    asm volatile("s_waitcnt vmcnt(4)" ::: "memory");  // tile0 landed; tile1 A0/B0 fly
    __builtin_amdgcn_s_barrier();

    for (int it = 0; it < NT / 2; ++it) {
        const int t = it * 2;
        const int k_t1 = ((t + 1) & (NT - 1)) * BK;  // & wraps final garbage
        const int k_t2 = ((t + 2) & (NT - 1)) * BK;  //  prefetches in-bounds
        const int k_t3 = ((t + 3) & (NT - 1)) * BK;  //  (never consumed)

        // ---- K-tile t (buf0)
        PHASE(A0p, B0p, 0, 0, 1, STAGE(As[1] + 8192, xb, m0 + 128, k_t1), );
        PHASE(A0p, B0p, 0, 1, 0, STAGE(Bs[1] + 8192, Wq, n0 + 128, k_t1), );
        PHASE(A0p, B0p, 1, 0, 1, STAGE(As[0],        xb, m0,       k_t2), );
        PHASE(A0p, B0p, 1, 1, 0, STAGE(Bs[0],        Wq, n0,       k_t2),
              asm volatile("s_waitcnt vmcnt(4)" ::: "memory"));

        // ---- K-tile t+1 (buf1)
        PHASE(A1p, B1p, 0, 0, 1, STAGE(As[0] + 8192, xb, m0 + 128, k_t2), );
        PHASE(A1p, B1p, 0, 1, 0, STAGE(Bs[0] + 8192, Wq, n0 + 128, k_t2), );
        PHASE(A1p, B1p, 1, 0, 1, STAGE(As[1],        xb, m0,       k_t3), );
        PHASE(A1p, B1p, 1, 1, 0, STAGE(Bs[1],        Wq, n0,       k_t3),
              asm volatile("s_waitcnt vmcnt(4)" ::: "memory"));
    }

    // drain leftover (garbage) prefetches before LDS deallocation at endpgm
    asm volatile("s_waitcnt vmcnt(0)" ::: "memory");

    // ---- epilogue: bias + store
    // C/D 16x16: col = lane&15, row = (lane>>4)*4 + reg  (m89-verified)
    const int cc  = lane & 15;
    const int rr4 = (lane >> 4) * 4;
    float bv[2][2];
#pragma unroll
    for (int nh = 0; nh < 2; ++nh)
#pragma unroll
        for (int fn = 0; fn < 2; ++fn)
            bv[nh][fn] = bias[n0 + nh * 128 + wn * 32 + fn * 16 + cc];

#pragma unroll
    for (int mh = 0; mh < 2; ++mh)
#pragma unroll
        for (int fm = 0; fm < 4; ++fm) {
            const int m = m0 + mh * 128 + wm * 64 + fm * 16 + rr4;
#pragma unroll
            for (int nh = 0; nh < 2; ++nh)
#pragma unroll
                for (int fn = 0; fn < 2; ++fn) {
                    const int n = n0 + nh * 128 + wn * 32 + fn * 16 + cc;
                    float* op = out + (size_t)m * OUT_F + n;
                    const f32x4 a = acc[mh * 4 + fm][nh * 2 + fn];
#pragma unroll
                    for (int r = 0; r < 4; ++r)
                        op[(size_t)r * OUT_F] = a[r] + bv[nh][fn];
                }
        }
}

// ---------------------------------------------------------------------------
extern "C" void kernel_launch(void* const* d_in, const int* in_sizes, int n_in,
                              void* d_out, int out_size, void* d_ws, size_t ws_size,
                              hipStream_t stream) {
    const float* x      = (const float*)d_in[0];   // [8,1024,4096] fp32
    const int*   qw     = (const int*)  d_in[1];   // [4096,4096] int32 codes
    const float* scales = (const float*)d_in[2];   // [4096,64] fp32
    const float* bias   = (const float*)d_in[3];   // [4096] fp32
    const float* lA     = (const float*)d_in[4];   // [4096,16] fp32
    const float* lB     = (const float*)d_in[5];   // [16,4096] fp32
    float* out = (float*)d_out;                    // [8,1024,4096] fp32

    // workspace layout (needs 96 MB)
    char* ws = (char*)d_ws;
    __hip_bfloat16* Wq = (__hip_bfloat16*)ws;                              // 32 MB
    __hip_bfloat16* xb = (__hip_bfloat16*)(ws + (size_t)32 * 1024 * 1024); // 64 MB

    // 1) merged prep: convert (16384 blocks) + dequant/fold (2048 blocks)
    prep_kernel<<<CONV_BLOCKS + DEQ_BLOCKS, 256, 0, stream>>>(
        x, qw, scales, lA, lB, xb, Wq);
    // 2) main GEMM (256x256 tiles, 8-phase) + bias epilogue
    qlora_gemm_kernel<<<dim3(512), dim3(512), 0, stream>>>(xb, Wq, bias, out);
}

// Round 3
// 594.093 us; speedup vs baseline: 1.0804x; 1.0412x over previous
//
#include <hip/hip_runtime.h>
#include <hip/hip_bf16.h>

#define IN_F 4096
#define OUT_F 4096
#define M_TOK 8192
#define RANK 16

typedef __attribute__((ext_vector_type(4))) float f32x4;
typedef __attribute__((ext_vector_type(8))) short short8;

struct alignas(16) bf16x8_s { __hip_bfloat16 v[8]; };

// ---------------------------------------------------------------------------
// Kernel 1a: streaming convert x fp32 -> bf16. Split from the merged prep
// kernel: standalone it compiles to ~16 VGPR -> full occupancy, and the
// grid-stride form (2048 blocks x 8 iters) avoids 16K one-shot micro-blocks.
// (Theory: merged kernel forced dequant's ~150 VGPR on the streaming part.)
// ---------------------------------------------------------------------------
#define CONV_BLOCKS 2048
#define CONV_ITERS (M_TOK * IN_F / (8 * 256 * CONV_BLOCKS))   // 8

__global__ __launch_bounds__(256) void conv_kernel(
    const float* __restrict__ x,
    __hip_bfloat16* __restrict__ xb) {
    size_t idx = (size_t)blockIdx.x * 256 + threadIdx.x;
    const size_t stride = (size_t)CONV_BLOCKS * 256;
#pragma unroll
    for (int it = 0; it < CONV_ITERS; ++it, idx += stride) {
        const size_t base = idx * 8;
        float4 v0 = *(const float4*)(x + base);
        float4 v1 = *(const float4*)(x + base + 4);
        bf16x8_s r;
        r.v[0] = __float2bfloat16(v0.x);
        r.v[1] = __float2bfloat16(v0.y);
        r.v[2] = __float2bfloat16(v0.z);
        r.v[3] = __float2bfloat16(v0.w);
        r.v[4] = __float2bfloat16(v1.x);
        r.v[5] = __float2bfloat16(v1.y);
        r.v[6] = __float2bfloat16(v1.z);
        r.v[7] = __float2bfloat16(v1.w);
        *(bf16x8_s*)(xb + base) = r;
    }
}

// ---------------------------------------------------------------------------
// Kernel 1b: dequant int4 codes -> bf16 with rank-16 LoRA folded in:
//   W[o][i] = bf16( scales[o][i/64]*(q-8) + 2*sum_r A[i][r]*B[r][o] )
// Body unchanged from the merged version (only the block-index base moved).
// ---------------------------------------------------------------------------
#define DEQ_BLOCKS 2048

__global__ __launch_bounds__(256) void deq_kernel(
    const int* __restrict__ q,
    const float* __restrict__ scales,
    const float* __restrict__ lA,   // [IN_F][RANK]
    const float* __restrict__ lB,   // [RANK][OUT_F]
    __hip_bfloat16* __restrict__ W) {
    const int tid = threadIdx.x;
    const int bid = blockIdx.x;                  // 0..2047
    const int o0 = (bid >> 1) * 4;               // block-uniform
    const int i0 = (bid & 1) * 2048 + tid * 8;

    float bw[16][4];
#pragma unroll
    for (int r = 0; r < 16; ++r)
#pragma unroll
        for (int oi = 0; oi < 4; ++oi)
            bw[r][oi] = 2.0f * lB[(size_t)r * OUT_F + o0 + oi];

    float fold[4][8];
#pragma unroll
    for (int e = 0; e < 8; ++e) {
        const float* ar = lA + (size_t)(i0 + e) * RANK;
        float4 a0 = *(const float4*)(ar + 0);
        float4 a1 = *(const float4*)(ar + 4);
        float4 a2 = *(const float4*)(ar + 8);
        float4 a3 = *(const float4*)(ar + 12);
#pragma unroll
        for (int oi = 0; oi < 4; ++oi) {
            float f = a0.x * bw[0][oi] + a0.y * bw[1][oi]
                    + a0.z * bw[2][oi] + a0.w * bw[3][oi]
                    + a1.x * bw[4][oi] + a1.y * bw[5][oi]
                    + a1.z * bw[6][oi] + a1.w * bw[7][oi]
                    + a2.x * bw[8][oi] + a2.y * bw[9][oi]
                    + a2.z * bw[10][oi] + a2.w * bw[11][oi]
                    + a3.x * bw[12][oi] + a3.y * bw[13][oi]
                    + a3.z * bw[14][oi] + a3.w * bw[15][oi];
            fold[oi][e] = f;
        }
    }

#pragma unroll
    for (int oi = 0; oi < 4; ++oi) {
        const int o = o0 + oi;
        const float s = scales[o * 64 + (i0 >> 6)];
        const int4* qp = (const int4*)(q + (size_t)o * IN_F + i0);
        int4 q0 = qp[0];
        int4 q1 = qp[1];
        bf16x8_s r;
        r.v[0] = __float2bfloat16(s * (float)(q0.x - 8) + fold[oi][0]);
        r.v[1] = __float2bfloat16(s * (float)(q0.y - 8) + fold[oi][1]);
        r.v[2] = __float2bfloat16(s * (float)(q0.z - 8) + fold[oi][2]);
        r.v[3] = __float2bfloat16(s * (float)(q0.w - 8) + fold[oi][3]);
        r.v[4] = __float2bfloat16(s * (float)(q1.x - 8) + fold[oi][4]);
        r.v[5] = __float2bfloat16(s * (float)(q1.y - 8) + fold[oi][5]);
        r.v[6] = __float2bfloat16(s * (float)(q1.z - 8) + fold[oi][6]);
        r.v[7] = __float2bfloat16(s * (float)(q1.w - 8) + fold[oi][7]);
        *(bf16x8_s*)(W + (size_t)o * IN_F + i0) = r;
    }
}

// ---------------------------------------------------------------------------
// Kernel 2: 256x256 8-phase GEMM. R2 change: phases restructured from
// (MH,NH)-quadrants to (MH,KK)-quadrants so LDS reads drop 32->24 KB per
// wave per K-tile (template-matching 8/4/8/4 reads): fb holds the wave's
// FULL 64-col B slice for one K-half (read once at p0/p2, reused at p1/p3);
// fa reads each A quarter exactly once. Phase order (MH,KK):
//   p0 (0,0): read fa(A0,k0) 4 + fb(B,k0) 4; stage Y.A1(t+1)
//   p1 (1,0): read fa(A1,k0) 4;              stage Y.B1(t+1)
//   p2 (0,1): read fa(A0,k1) 4 + fb(B,k1) 4; (no stage)
//   p3 (1,1): read fa(A1,k1) 4;              stage X.A0+X.B0(t+2); vmcnt(4)
// Race audit (last-reader table: X.A0/B0/B1 last read p2, X.A1 last read p3):
//   p0 stage Y.A1 -> Y.A1 last read t-1 p3 (drained at its lgkm0+barrier) OK
//   p1 stage Y.B1 -> last read t-1 p2 OK
//   p3 stage X.A0/X.B0 -> last read THIS tile p2; p2's lgkm0+end-barrier
//     precede p3 OK. X.A1 (last read p3 itself) is staged at t+1 p0 OK.
// vmcnt(4) at p3: outstanding <=12 (t-1p3:4 + p0:2 + p1:2 + p3:4); keeps
// p3's 4 (tile t+2 data, drained by t+1 p3's vmcnt before t+2 p0) in flight,
// drains everything tile t+1 needs. Never vmcnt(0) in the loop.
// ---------------------------------------------------------------------------
#define BK 64
#define NT (IN_F / BK)   // 64 K-tiles

__device__ __forceinline__ short8 ldfrag(const short* p, int half, int row, int gran) {
    // swizzled read: LDS granule slot (gran ^ (row&7)) holds global granule gran
    return *(const short8*)(p + half * 8192 + row * 64 + ((gran ^ (row & 7)) * 8));
}

// one half-tile stage: 128 rows x 64 cols bf16, 2 issues x (8 waves x 8 rows).
// LDS dest linear (wave-uniform base + lane*16B); st-swizzle applied by
// permuting the GLOBAL source granule (rule 21: both-sides-or-neither).
#define STAGE(LDSbuf, SRC, ROW0, K0)                                          \
    {                                                                         \
        _Pragma("unroll")                                                     \
        for (int j = 0; j < 2; ++j) {                                         \
            const __hip_bfloat16* g = (SRC) +                                 \
                (size_t)((ROW0) + j * 64 + wave * 8 + srow) * IN_F + (K0) + sgc; \
            __builtin_amdgcn_global_load_lds(                                 \
                (const __attribute__((address_space(1))) void*)g,             \
                (__attribute__((address_space(3))) void*)((LDSbuf) + (j * 64 + wave * 8) * 64), \
                16, 0, 0);                                                    \
        }                                                                     \
    }

#define PHASE(ABUF, BBUF, MH, KK, READB, STAGE_CODE, WAITCODE)                \
    {                                                                         \
        _Pragma("unroll") for (int f = 0; f < 4; ++f)                         \
            fa[f] = ldfrag(ABUF, MH, wm * 64 + f * 16 + fr, (KK) * 4 + fc);   \
        if (READB) {                                                          \
            _Pragma("unroll") for (int g2 = 0; g2 < 4; ++g2)                  \
                fb[g2] = ldfrag(BBUF, bhalf, brow0 + g2 * 16 + fr, (KK) * 4 + fc); \
        }                                                                     \
        STAGE_CODE;                                                           \
        WAITCODE;                                                             \
        __builtin_amdgcn_s_barrier();                                         \
        asm volatile("s_waitcnt lgkmcnt(0)" ::: "memory");                    \
        __builtin_amdgcn_sched_barrier(0);                                    \
        __builtin_amdgcn_s_setprio(1);                                        \
        _Pragma("unroll") for (int f = 0; f < 4; ++f)                         \
        _Pragma("unroll") for (int g2 = 0; g2 < 4; ++g2)                      \
            acc[(MH) * 4 + f][g2] =                                           \
                __builtin_amdgcn_mfma_f32_16x16x32_bf16(                      \
                    fa[f], fb[g2], acc[(MH) * 4 + f][g2], 0, 0, 0);           \
        __builtin_amdgcn_s_setprio(0);                                        \
        __builtin_amdgcn_s_barrier();                                         \
    }

__global__ __launch_bounds__(512, 2) void qlora_gemm_kernel(
    const __hip_bfloat16* __restrict__ xb,   // [M_TOK][IN_F]
    const __hip_bfloat16* __restrict__ Wq,   // [OUT_F][IN_F]  (B^T layout)
    const float* __restrict__ bias,          // [OUT_F]
    float* __restrict__ out) {               // [M_TOK][OUT_F]
    __shared__ __hip_bfloat16 As[2][16384];  // [dbuf][half(2) x 128 x 64] = 64 KB
    __shared__ __hip_bfloat16 Bs[2][16384];  // 64 KB

    const int tid  = threadIdx.x;
    const int wave = tid >> 6;
    const int lane = tid & 63;
    const int wm = wave >> 2;                // 0..1  (M half of wave grid)
    const int wn = wave & 3;                 // 0..3  (N quarter: 64 cols each)

    // T1: bijective XCD swizzle (nwg=512, 512%8==0)
    const int wg = ((int)blockIdx.x & 7) * 64 + ((int)blockIdx.x >> 3);
    const int bx = wg & 15;                  // 16 N-tiles
    const int by = wg >> 4;                  // 32 M-tiles
    const int m0 = by * 256;
    const int n0 = bx * 256;

    f32x4 acc[8][4];
#pragma unroll
    for (int i = 0; i < 8; ++i)
#pragma unroll
        for (int j = 0; j < 4; ++j)
            acc[i][j] = (f32x4){0.f, 0.f, 0.f, 0.f};

    // staging lane geometry: LDS slot p of row r holds global granule (p^(r&7))
    const int srow = lane >> 3;
    const int sgc  = ((lane & 7) ^ srow) * 8;

    // fragment read geometry (16x16x32): row = lane&15, k-granule = lane>>4
    const int fr = lane & 15;
    const int fc = lane >> 4;

    // wave's B slice: contiguous 64 cols = n0 + wn*64; in LDS halves of 128:
    const int bhalf = wn >> 1;
    const int brow0 = (wn & 1) * 64;

    const short* A0p = (const short*)As[0];
    const short* A1p = (const short*)As[1];
    const short* B0p = (const short*)Bs[0];
    const short* B1p = (const short*)Bs[1];

    short8 fa[4];
    short8 fb[4];

    // prologue: tile0 (buf0) all 4 regions; tile1 (buf1) A0,B0 (its A1,B1
    // staged in tile0's p0/p1, matching steady state)
    STAGE(As[0],        xb, m0,       0);
    STAGE(Bs[0],        Wq, n0,       0);
    STAGE(As[0] + 8192, xb, m0 + 128, 0);
    STAGE(Bs[0] + 8192, Wq, n0 + 128, 0);
    STAGE(As[1],        xb, m0,       BK);
    STAGE(Bs[1],        Wq, n0,       BK);
    asm volatile("s_waitcnt vmcnt(4)" ::: "memory");  // buf0 landed; buf1 A0/B0 fly
    __builtin_amdgcn_s_barrier();

    for (int it = 0; it < NT / 2; ++it) {
        const int t = it * 2;
        const int k_t1 = ((t + 1) & (NT - 1)) * BK;  // & wraps final garbage
        const int k_t2 = ((t + 2) & (NT - 1)) * BK;  //  prefetches in-bounds
        const int k_t3 = ((t + 3) & (NT - 1)) * BK;  //  (never consumed)

        // ---- K-tile t (buf0)
        PHASE(A0p, B0p, 0, 0, 1, STAGE(As[1] + 8192, xb, m0 + 128, k_t1), );
        PHASE(A0p, B0p, 1, 0, 0, STAGE(Bs[1] + 8192, Wq, n0 + 128, k_t1), );
        PHASE(A0p, B0p, 0, 1, 1, , );
        PHASE(A0p, B0p, 1, 1, 0,
              { STAGE(As[0], xb, m0, k_t2); STAGE(Bs[0], Wq, n0, k_t2); },
              asm volatile("s_waitcnt vmcnt(4)" ::: "memory"));

        // ---- K-tile t+1 (buf1)
        PHASE(A1p, B1p, 0, 0, 1, STAGE(As[0] + 8192, xb, m0 + 128, k_t2), );
        PHASE(A1p, B1p, 1, 0, 0, STAGE(Bs[0] + 8192, Wq, n0 + 128, k_t2), );
        PHASE(A1p, B1p, 0, 1, 1, , );
        PHASE(A1p, B1p, 1, 1, 0,
              { STAGE(As[1], xb, m0, k_t3); STAGE(Bs[1], Wq, n0, k_t3); },
              asm volatile("s_waitcnt vmcnt(4)" ::: "memory"));
    }

    // drain leftover (garbage) prefetches before LDS deallocation at endpgm
    asm volatile("s_waitcnt vmcnt(0)" ::: "memory");

    // ---- epilogue: bias + store
    // C/D 16x16: col = lane&15, row = (lane>>4)*4 + reg  (m89-verified)
    const int cc  = lane & 15;
    const int rr4 = (lane >> 4) * 4;
    float bv[4];
#pragma unroll
    for (int g2 = 0; g2 < 4; ++g2)
        bv[g2] = bias[n0 + wn * 64 + g2 * 16 + cc];

#pragma unroll
    for (int mh = 0; mh < 2; ++mh)
#pragma unroll
        for (int f = 0; f < 4; ++f) {
            const int m = m0 + mh * 128 + wm * 64 + f * 16 + rr4;
#pragma unroll
            for (int g2 = 0; g2 < 4; ++g2) {
                const int n = n0 + wn * 64 + g2 * 16 + cc;
                float* op = out + (size_t)m * OUT_F + n;
                const f32x4 a = acc[mh * 4 + f][g2];
#pragma unroll
                for (int r = 0; r < 4; ++r)
                    op[(size_t)r * OUT_F] = a[r] + bv[g2];
            }
        }
}

// ---------------------------------------------------------------------------
extern "C" void kernel_launch(void* const* d_in, const int* in_sizes, int n_in,
                              void* d_out, int out_size, void* d_ws, size_t ws_size,
                              hipStream_t stream) {
    const float* x      = (const float*)d_in[0];   // [8,1024,4096] fp32
    const int*   qw     = (const int*)  d_in[1];   // [4096,4096] int32 codes
    const float* scales = (const float*)d_in[2];   // [4096,64] fp32
    const float* bias   = (const float*)d_in[3];   // [4096] fp32
    const float* lA     = (const float*)d_in[4];   // [4096,16] fp32
    const float* lB     = (const float*)d_in[5];   // [16,4096] fp32
    float* out = (float*)d_out;                    // [8,1024,4096] fp32

    // workspace layout (needs 96 MB)
    char* ws = (char*)d_ws;
    __hip_bfloat16* Wq = (__hip_bfloat16*)ws;                              // 32 MB
    __hip_bfloat16* xb = (__hip_bfloat16*)(ws + (size_t)32 * 1024 * 1024); // 64 MB

    // 1a) streaming x convert (grid-stride, full occupancy standalone)
    conv_kernel<<<CONV_BLOCKS, 256, 0, stream>>>(x, xb);
    // 1b) dequant + LoRA fold
    deq_kernel<<<DEQ_BLOCKS, 256, 0, stream>>>(qw, scales, lA, lB, Wq);
    // 2) main GEMM (256x256 tiles, 8-phase) + bias epilogue
    qlora_gemm_kernel<<<dim3(512), dim3(512), 0, stream>>>(xb, Wq, bias, out);
}